// Round 13
// baseline (179.226 us; speedup 1.0000x reference)
//
#include <hip/hip_runtime.h>
#include <math.h>

#define NPIX 4096
#define CHSZ 3145728   // one num partial: 24*32*4096 floats
#define NRMSZ 98304    // one nrm partial: 24*4096 floats

// ---------------------------------------------------------------------------
// DPP-based 64-lane inclusive scan (VALU only, no LDS traffic)
// ---------------------------------------------------------------------------
template <int CTRL, int RM>
__device__ __forceinline__ float dpp_add(float x) {
    int xi = __builtin_bit_cast(int, x);
    int sh = __builtin_amdgcn_update_dpp(0, xi, CTRL, RM, 0xf, false);
    return x + __builtin_bit_cast(float, sh);
}

__device__ __forceinline__ float wave_iscan(float x) {
    x = dpp_add<0x111, 0xf>(x);   // row_shr:1
    x = dpp_add<0x112, 0xf>(x);   // row_shr:2
    x = dpp_add<0x114, 0xf>(x);   // row_shr:4
    x = dpp_add<0x118, 0xf>(x);   // row_shr:8
    x = dpp_add<0x142, 0xa>(x);   // row_bcast:15 -> rows 1,3
    x = dpp_add<0x143, 0xc>(x);   // row_bcast:31 -> rows 2,3
    return x;
}

// LDS-only barrier: drain lgkm (ds ops) but leave global loads in flight.
__device__ __forceinline__ void lds_barrier() {
    asm volatile("s_waitcnt lgkmcnt(0)" ::: "memory");
    __builtin_amdgcn_s_barrier();
    __builtin_amdgcn_sched_barrier(0);
}

// ---------------------------------------------------------------------------
// Kernel 1: fused QKV 1x1-conv GEMM, 128px x 32out tiles + register prefetch
// (unchanged from R7/R9).
// ---------------------------------------------------------------------------
__global__ __launch_bounds__(256) void qkv_kernel(
    const float* __restrict__ x, const float* __restrict__ Wq,
    const float* __restrict__ Wk, const float* __restrict__ Wv,
    float* __restrict__ qo, float* __restrict__ ko, float* __restrict__ vo)
{
    const int pt = blockIdx.x * 128;
    const int ot = blockIdx.y * 32;
    const int mat = blockIdx.z;
    const float* __restrict__ W = (mat == 0) ? Wq : ((mat == 1) ? Wk : Wv);
    float* __restrict__ out = (mat == 0) ? qo : ((mat == 1) ? ko : vo);

    __shared__ __align__(16) float Xs[32][132];
    __shared__ __align__(16) float Wt[32][36];   // [c][o]

    const int t = threadIdx.x;
    const int pc = t & 31;
    const int oc = t >> 5;
    const int xc = t >> 5;
    const int xp = (t & 31) << 2;
    const int lo = t >> 3;
    const int lg = (t & 7) << 2;

    float4 xf[4];
    float4 wf;
#pragma unroll
    for (int i = 0; i < 4; i++)
        xf[i] = *reinterpret_cast<const float4*>(x + (xc + 8 * i) * NPIX + pt + xp);
    wf = *reinterpret_cast<const float4*>(W + (ot + lo) * 256 + lg);

    float acc[4][4];
#pragma unroll
    for (int j = 0; j < 4; j++)
#pragma unroll
        for (int i = 0; i < 4; i++) acc[j][i] = 0.f;

    for (int kt = 0; kt < 256; kt += 32) {
#pragma unroll
        for (int i = 0; i < 4; i++)
            *reinterpret_cast<float4*>(&Xs[xc + 8 * i][xp]) = xf[i];
        Wt[lg + 0][lo] = wf.x;
        Wt[lg + 1][lo] = wf.y;
        Wt[lg + 2][lo] = wf.z;
        Wt[lg + 3][lo] = wf.w;
        __syncthreads();
        if (kt + 32 < 256) {
#pragma unroll
            for (int i = 0; i < 4; i++)
                xf[i] = *reinterpret_cast<const float4*>(
                    x + (kt + 32 + xc + 8 * i) * NPIX + pt + xp);
            wf = *reinterpret_cast<const float4*>(W + (ot + lo) * 256 + kt + 32 + lg);
        }
#pragma unroll
        for (int kk = 0; kk < 32; kk++) {
            float4 a = *reinterpret_cast<const float4*>(&Xs[kk][pc << 2]);
            float av[4] = {a.x, a.y, a.z, a.w};
            float4 b4 = *reinterpret_cast<const float4*>(&Wt[kk][oc << 2]);
            float bv[4] = {b4.x, b4.y, b4.z, b4.w};
#pragma unroll
            for (int j = 0; j < 4; j++)
#pragma unroll
                for (int i = 0; i < 4; i++)
                    acc[j][i] = fmaf(bv[j], av[i], acc[j][i]);
        }
        __syncthreads();
    }

    if (mat < 2) {
#pragma unroll
        for (int j = 0; j < 4; j++) {
            const int o = ot + (oc << 2) + j;
            float4 r;
            r.x = 1.f / (1.f + __expf(-acc[j][0]));
            r.y = 1.f / (1.f + __expf(-acc[j][1]));
            r.z = 1.f / (1.f + __expf(-acc[j][2]));
            r.w = 1.f / (1.f + __expf(-acc[j][3]));
            *reinterpret_cast<float4*>(out + o * NPIX + pt + (pc << 2)) = r;
        }
    } else {
        float* scratch = &Xs[0][0];
        __syncthreads();
#pragma unroll
        for (int i = 0; i < 4; i++) {
            float ss = 0.f;
#pragma unroll
            for (int j = 0; j < 4; j++) ss += acc[j][i] * acc[j][i];
            scratch[oc * 128 + (pc << 2) + i] = ss;
        }
        __syncthreads();
        float scale[4];
#pragma unroll
        for (int i = 0; i < 4; i++) {
            float tot = 0.f;
#pragma unroll
            for (int g = 0; g < 8; g++) tot += scratch[g * 128 + (pc << 2) + i];
            scale[i] = 1.f / fmaxf(sqrtf(tot), 1e-12f);
        }
#pragma unroll
        for (int j = 0; j < 4; j++) {
            const int o = ot + (oc << 2) + j;
            float4 r;
            r.x = acc[j][0] * scale[0];
            r.y = acc[j][1] * scale[1];
            r.z = acc[j][2] * scale[2];
            r.w = acc[j][3] * scale[3];
            *reinterpret_cast<float4*>(out + o * NPIX + pt + (pc << 2)) = r;
        }
    }
}

// ---------------------------------------------------------------------------
// Kernel 2: fused integral-image + windowed contraction, 512 threads (8 waves).
// R13: integral image stored Y-MAJOR P[y][x] with EXCLUSIVE prefixes, so all
// clamps are index clamps: row 0 = zeros (ylo<0), col 0 = zeros (xlo<0),
// row/col 64 = totals (hi clamps). No pads, no branches in phase 4.
// Phase-4 thread map: 4 consecutive-x pixels per thread at one row ->
// every corner fetch is a 16-lane-contiguous float4 (conflict-free);
// quads never straddle clamps (x4, hw == 0 mod 4); boundary = splat select.
// Stores: 8 contiguous b32 row-writes/lane. q loads & num/nrm writes: float4.
// Keeps R12's 1-barrier double-buffered pipeline (correct, neutral).
// All register-array loops compile-time (R8); one-arg launch_bounds (R4).
// ---------------------------------------------------------------------------
template <int PD>
__global__ __launch_bounds__(512) void attn_kernel(
    const float* __restrict__ q, const float* __restrict__ k,
    const float* __restrict__ v, float* __restrict__ num, float* __restrict__ nrm)
{
    const int f = blockIdx.x;          // 0..32 (32 == norm slot)
    const int head = blockIdx.y;       // 0..7
    const int dg = blockIdx.z;         // 0..(32/PD - 1)
    const bool isnorm = (f == 32);

    const float* __restrict__ kh = k + (head * 32 + dg * PD) * NPIX;
    const float* __restrict__ qh = q + (head * 32 + dg * PD) * NPIX;
    const float* __restrict__ vf = v + (head * 32 + (isnorm ? 0 : f)) * NPIX;

    __shared__ __align__(16) float Pt[2][65][68];   // y-major, 2 x 17,680 B
    __shared__ float csum[2][8][68];

    const int t = threadIdx.x;
    const int lane = t & 63;
    const int wv = t >> 6;             // 0..7
    const int ty = t >> 4;             // phase-4 row (0..31)
    const int x4 = (t & 15) << 2;      // phase-4 x-quad base

    // zero-init both buffers once; col 0 and row 0 stay zero forever
    for (int i = t; i < 2 * 65 * 68; i += 512) (&Pt[0][0][0])[i] = 0.f;

    float vreg[8], kcur[8];
#pragma unroll
    for (int i = 0; i < 8; i++) {
        const int r = wv * 8 + i;
        vreg[i] = isnorm ? 1.f : vf[r * 64 + lane];
        kcur[i] = kh[r * 64 + lane];
    }

    float acc[3][8];
#pragma unroll
    for (int w = 0; w < 3; w++)
#pragma unroll
        for (int i = 0; i < 8; i++) acc[w][i] = 0.f;

    // prologue: iscan(0) -> pv, csum[0]; prefetch k(1)
    float pv[8], runcur;
    {
        float run = 0.f;
#pragma unroll
        for (int i = 0; i < 8; i++) {
            float rs = wave_iscan(kcur[i] * vreg[i]);
            pv[i] = run;               // exclusive prefix: P row (8*wv + i)
            run += rs;
        }
        csum[0][wv][lane] = run;
        runcur = run;
        if (PD > 1) {
#pragma unroll
            for (int i = 0; i < 8; i++)
                kcur[i] = kh[1 * NPIX + (wv * 8 + i) * 64 + lane];
        }
    }
    lds_barrier();                     // zero-init + csum(0) visible

    float pvn[8], runn;
    for (int dd = 0; dd < PD; dd++) {
        const int b = dd & 1;
        // off(dd) + store P(dd) rows into Pt[b] (contiguous along lane)
        float off = 0.f;
#pragma unroll
        for (int w2 = 0; w2 < 7; w2++) if (w2 < wv) off += csum[b][w2][lane];
#pragma unroll
        for (int i = 0; i < 8; i++)
            Pt[b][wv * 8 + i][lane + 1] = pv[i] + off;
        if (wv == 7) Pt[b][64][lane + 1] = off + runcur;   // row 64 = totals
        // qload(dd) as two float4 (consumed in phase4 after the barrier)
        float4 qv4[2];
        qv4[0] = *reinterpret_cast<const float4*>(qh + dd * NPIX + ty * 64 + x4);
        qv4[1] = *reinterpret_cast<const float4*>(qh + dd * NPIX + (ty + 32) * 64 + x4);
        // iscan(dd+1) into pvn + csum[b^1]; then reuse kcur for k(dd+2)
        if (dd + 1 < PD) {
            float run = 0.f;
#pragma unroll
            for (int i = 0; i < 8; i++) {
                float rs = wave_iscan(kcur[i] * vreg[i]);
                pvn[i] = run;
                run += rs;
            }
            csum[b ^ 1][wv][lane] = run;
            runn = run;
            if (dd + 2 < PD) {
#pragma unroll
                for (int i = 0; i < 8; i++)
                    kcur[i] = kh[(dd + 2) * NPIX + (wv * 8 + i) * 64 + lane];
            }
        }
        lds_barrier();                 // the ONLY barrier per d-iter
        // phase4(dd): branch-free clamped corner reads from Pt[b]
#pragma unroll
        for (int g = 0; g < 2; g++) {
            const int y = ty + 32 * g;
            const float qx = (g == 0) ? qv4[0].x : qv4[1].x;
            const float qy = (g == 0) ? qv4[0].y : qv4[1].y;
            const float qz = (g == 0) ? qv4[0].z : qv4[1].z;
            const float qw = (g == 0) ? qv4[0].w : qv4[1].w;
#pragma unroll
            for (int w = 0; w < 3; w++) {
                const int hw = 32 >> w;
                const int yhi = min(y + hw, 64);
                const int ylo = max(y - hw, 0);     // row 0 = zeros
                const int xh = x4 + hw;
                const int xl = x4 - hw;
                const int xhc = min(xh, 64);
                const int xlc = max(xl, 0);
                float4 A4 = *reinterpret_cast<const float4*>(&Pt[b][yhi][xhc]);
                float4 C4 = *reinterpret_cast<const float4*>(&Pt[b][ylo][xhc]);
                float4 B4 = *reinterpret_cast<const float4*>(&Pt[b][yhi][xlc]);
                float4 E4 = *reinterpret_cast<const float4*>(&Pt[b][ylo][xlc]);
                if (xh >= 64) {        // whole quad clamps to col 64: splat
                    A4.y = A4.x; A4.z = A4.x; A4.w = A4.x;
                    C4.y = C4.x; C4.z = C4.x; C4.w = C4.x;
                }
                if (xl < 0) {          // whole quad clamps to col 0: zeros
                    B4 = make_float4(0.f, 0.f, 0.f, 0.f);
                    E4 = B4;
                }
                acc[w][g * 4 + 0] = fmaf(qx, (A4.x - B4.x) - (C4.x - E4.x), acc[w][g * 4 + 0]);
                acc[w][g * 4 + 1] = fmaf(qy, (A4.y - B4.y) - (C4.y - E4.y), acc[w][g * 4 + 1]);
                acc[w][g * 4 + 2] = fmaf(qz, (A4.z - B4.z) - (C4.z - E4.z), acc[w][g * 4 + 2]);
                acc[w][g * 4 + 3] = fmaf(qw, (A4.w - B4.w) - (C4.w - E4.w), acc[w][g * 4 + 3]);
            }
        }
        // rotate pipeline registers (static indices)
        if (dd + 1 < PD) {
#pragma unroll
            for (int i = 0; i < 8; i++) pv[i] = pvn[i];
            runcur = runn;
        }
    }

    // epilogue: float4 coalesced writes
    float* __restrict__ nout = num + (size_t)dg * CHSZ;
    float* __restrict__ rout = nrm + (size_t)dg * NRMSZ;
#pragma unroll
    for (int w = 0; w < 3; w++) {
#pragma unroll
        for (int g = 0; g < 2; g++) {
            const int px = (ty + 32 * g) * 64 + x4;
            float4 r = make_float4(acc[w][g * 4 + 0], acc[w][g * 4 + 1],
                                   acc[w][g * 4 + 2], acc[w][g * 4 + 3]);
            if (isnorm)
                *reinterpret_cast<float4*>(rout + (w * 8 + head) * NPIX + px) = r;
            else
                *reinterpret_cast<float4*>(nout + ((w * 8 + head) * 32 + f) * NPIX + px) = r;
        }
    }
}

// ---------------------------------------------------------------------------
// Kernel 3: final 1x1 conv partial; acc[4][4], 64px x 64out tiles, K-split
// across z (12 of 24 channels each). grid (64, 4, 2). (unchanged from R11)
// ---------------------------------------------------------------------------
template <int NS>
__global__ __launch_bounds__(256) void out_kernel(
    const float* __restrict__ num, const float* __restrict__ nrm,
    const float* __restrict__ Wout, float* __restrict__ obuf)
{
    const int pt = blockIdx.x * 64;
    const int ot = blockIdx.y * 64;
    const int kt0 = blockIdx.z * 12;
    __shared__ __align__(16) float As[32][68];
    __shared__ __align__(16) float Wt[32][68];   // [c][o]
    const int t = threadIdx.x;
    const int pc = t & 15;
    const int oc = t >> 4;
    const int xc = t >> 4;
    const int xp = (t & 15) << 2;
    const int lo = t & 63;
    const int lc = (t >> 6) << 2;

    float4 nv[NS][2], mv[NS], wf[2];
#pragma unroll
    for (int s = 0; s < NS; s++) {
#pragma unroll
        for (int i = 0; i < 2; i++)
            nv[s][i] = *reinterpret_cast<const float4*>(
                num + (size_t)s * CHSZ + (size_t)(kt0 * 32 + xc + 16 * i) * NPIX + pt + xp);
        mv[s] = *reinterpret_cast<const float4*>(
            nrm + (size_t)s * NRMSZ + kt0 * NPIX + pt + xp);
    }
    wf[0] = *reinterpret_cast<const float4*>(Wout + (ot + lo) * 768 + kt0 * 32 + lc);
    wf[1] = *reinterpret_cast<const float4*>(Wout + (ot + lo) * 768 + kt0 * 32 + lc + 16);

    float acc[4][4];
#pragma unroll
    for (int j = 0; j < 4; j++)
#pragma unroll
        for (int i = 0; i < 4; i++) acc[j][i] = 0.f;

    for (int kt = kt0; kt < kt0 + 12; kt++) {
        float4 ms = mv[0];
#pragma unroll
        for (int s = 1; s < NS; s++) {
            ms.x += mv[s].x; ms.y += mv[s].y; ms.z += mv[s].z; ms.w += mv[s].w;
        }
        float4 rv;
        rv.x = 1.f / (ms.x + 1e-6f); rv.y = 1.f / (ms.y + 1e-6f);
        rv.z = 1.f / (ms.z + 1e-6f); rv.w = 1.f / (ms.w + 1e-6f);
#pragma unroll
        for (int i = 0; i < 2; i++) {
            float4 r = nv[0][i];
#pragma unroll
            for (int s = 1; s < NS; s++) {
                r.x += nv[s][i].x; r.y += nv[s][i].y;
                r.z += nv[s][i].z; r.w += nv[s][i].w;
            }
            r.x *= rv.x; r.y *= rv.y; r.z *= rv.z; r.w *= rv.w;
            *reinterpret_cast<float4*>(&As[xc + 16 * i][xp]) = r;
        }
#pragma unroll
        for (int i = 0; i < 2; i++) {
            Wt[lc + 16 * i + 0][lo] = wf[i].x;
            Wt[lc + 16 * i + 1][lo] = wf[i].y;
            Wt[lc + 16 * i + 2][lo] = wf[i].z;
            Wt[lc + 16 * i + 3][lo] = wf[i].w;
        }
        __syncthreads();
        if (kt + 1 < kt0 + 12) {
#pragma unroll
            for (int s = 0; s < NS; s++) {
#pragma unroll
                for (int i = 0; i < 2; i++)
                    nv[s][i] = *reinterpret_cast<const float4*>(
                        num + (size_t)s * CHSZ +
                        (size_t)((kt + 1) * 32 + xc + 16 * i) * NPIX + pt + xp);
                mv[s] = *reinterpret_cast<const float4*>(
                    nrm + (size_t)s * NRMSZ + (kt + 1) * NPIX + pt + xp);
            }
            wf[0] = *reinterpret_cast<const float4*>(
                Wout + (ot + lo) * 768 + (kt + 1) * 32 + lc);
            wf[1] = *reinterpret_cast<const float4*>(
                Wout + (ot + lo) * 768 + (kt + 1) * 32 + lc + 16);
        }
#pragma unroll
        for (int kk = 0; kk < 32; kk++) {
            float4 a = *reinterpret_cast<const float4*>(&As[kk][pc << 2]);
            float av[4] = {a.x, a.y, a.z, a.w};
            float4 b4 = *reinterpret_cast<const float4*>(&Wt[kk][oc << 2]);
            float bv[4] = {b4.x, b4.y, b4.z, b4.w};
#pragma unroll
            for (int j = 0; j < 4; j++)
#pragma unroll
                for (int i = 0; i < 4; i++)
                    acc[j][i] = fmaf(bv[j], av[i], acc[j][i]);
        }
        __syncthreads();
    }

    float* __restrict__ ob = obuf + (size_t)blockIdx.z * 1048576;
#pragma unroll
    for (int j = 0; j < 4; j++) {
        const int o = ot + (oc << 2) + j;
        float4 r;
        r.x = acc[j][0]; r.y = acc[j][1]; r.z = acc[j][2]; r.w = acc[j][3];
        *reinterpret_cast<float4*>(ob + o * NPIX + pt + (pc << 2)) = r;
    }
}

// ---------------------------------------------------------------------------
// Kernel 4: merge K-split partials + bias. (unchanged from R11)
// ---------------------------------------------------------------------------
__global__ __launch_bounds__(256) void kmerge_kernel(
    const float* __restrict__ obuf, const float* __restrict__ bout,
    float* __restrict__ out)
{
    const int i4 = (blockIdx.x * 256 + threadIdx.x) * 4;
    const float bb = bout[i4 >> 12];
    float4 a = *reinterpret_cast<const float4*>(obuf + i4);
    float4 b = *reinterpret_cast<const float4*>(obuf + 1048576 + i4);
    float4 r;
    r.x = a.x + b.x + bb;
    r.y = a.y + b.y + bb;
    r.z = a.z + b.z + bb;
    r.w = a.w + b.w + bb;
    *reinterpret_cast<float4*>(out + i4) = r;
}

extern "C" void kernel_launch(void* const* d_in, const int* in_sizes, int n_in,
                              void* d_out, int out_size, void* d_ws, size_t ws_size,
                              hipStream_t stream)
{
    const float* x    = (const float*)d_in[0];
    const float* Wq   = (const float*)d_in[1];
    const float* Wk   = (const float*)d_in[2];
    const float* Wv   = (const float*)d_in[3];
    const float* Wout = (const float*)d_in[4];
    const float* bout = (const float*)d_in[5];
    float* out = (float*)d_out;

    float* ws = (float*)d_ws;
    float* q   = ws;                  // 1,048,576 floats
    float* k   = ws + 1048576;
    float* v   = ws + 2097152;
    float* num = ws + 3145728;        // NS partials of CHSZ, then NS of NRMSZ
    float* obuf = ws;                 // 2 x 1,048,576 — aliases dead q/k
    const size_t fl = ws_size / 4;

    qkv_kernel<<<dim3(32, 8, 3), 256, 0, stream>>>(x, Wq, Wk, Wv, q, k, v);

    if (fl >= 3145728 + (size_t)4 * (CHSZ + NRMSZ)) {        // NS = 4
        float* nrm = num + (size_t)4 * CHSZ;
        attn_kernel<8><<<dim3(33, 8, 4), 512, 0, stream>>>(q, k, v, num, nrm);
        out_kernel<4><<<dim3(64, 4, 2), 256, 0, stream>>>(num, nrm, Wout, obuf);
    } else if (fl >= 3145728 + (size_t)2 * (CHSZ + NRMSZ)) { // NS = 2
        float* nrm = num + (size_t)2 * CHSZ;
        attn_kernel<16><<<dim3(33, 8, 2), 512, 0, stream>>>(q, k, v, num, nrm);
        out_kernel<2><<<dim3(64, 4, 2), 256, 0, stream>>>(num, nrm, Wout, obuf);
    } else {                                                 // NS = 1
        float* nrm = num + CHSZ;
        attn_kernel<32><<<dim3(33, 8, 1), 512, 0, stream>>>(q, k, v, num, nrm);
        out_kernel<1><<<dim3(64, 4, 2), 256, 0, stream>>>(num, nrm, Wout, obuf);
    }
    kmerge_kernel<<<dim3(1024), 256, 0, stream>>>(obuf, bout, out);
}

// Round 14
// 147.957 us; speedup vs baseline: 1.2113x; 1.2113x over previous
//
#include <hip/hip_runtime.h>
#include <math.h>

#define NPIX 4096
#define CHSZ 3145728   // one num partial: 24*32*4096 floats
#define NRMSZ 98304    // one nrm partial: 24*4096 floats

// ---------------------------------------------------------------------------
// DPP-based 64-lane inclusive scan (VALU only, no LDS traffic)
// ---------------------------------------------------------------------------
template <int CTRL, int RM>
__device__ __forceinline__ float dpp_add(float x) {
    int xi = __builtin_bit_cast(int, x);
    int sh = __builtin_amdgcn_update_dpp(0, xi, CTRL, RM, 0xf, false);
    return x + __builtin_bit_cast(float, sh);
}

__device__ __forceinline__ float wave_iscan(float x) {
    x = dpp_add<0x111, 0xf>(x);   // row_shr:1
    x = dpp_add<0x112, 0xf>(x);   // row_shr:2
    x = dpp_add<0x114, 0xf>(x);   // row_shr:4
    x = dpp_add<0x118, 0xf>(x);   // row_shr:8
    x = dpp_add<0x142, 0xa>(x);   // row_bcast:15 -> rows 1,3
    x = dpp_add<0x143, 0xc>(x);   // row_bcast:31 -> rows 2,3
    return x;
}

// LDS-only barrier: drain lgkm (ds ops) but leave global loads in flight.
__device__ __forceinline__ void lds_barrier() {
    asm volatile("s_waitcnt lgkmcnt(0)" ::: "memory");
    __builtin_amdgcn_s_barrier();
    __builtin_amdgcn_sched_barrier(0);
}

// ---------------------------------------------------------------------------
// Kernel 1: fused QKV 1x1-conv GEMM, 128px x 32out tiles + register prefetch
// (unchanged from R7/R9).
// ---------------------------------------------------------------------------
__global__ __launch_bounds__(256) void qkv_kernel(
    const float* __restrict__ x, const float* __restrict__ Wq,
    const float* __restrict__ Wk, const float* __restrict__ Wv,
    float* __restrict__ qo, float* __restrict__ ko, float* __restrict__ vo)
{
    const int pt = blockIdx.x * 128;
    const int ot = blockIdx.y * 32;
    const int mat = blockIdx.z;
    const float* __restrict__ W = (mat == 0) ? Wq : ((mat == 1) ? Wk : Wv);
    float* __restrict__ out = (mat == 0) ? qo : ((mat == 1) ? ko : vo);

    __shared__ __align__(16) float Xs[32][132];
    __shared__ __align__(16) float Wt[32][36];   // [c][o]

    const int t = threadIdx.x;
    const int pc = t & 31;
    const int oc = t >> 5;
    const int xc = t >> 5;
    const int xp = (t & 31) << 2;
    const int lo = t >> 3;
    const int lg = (t & 7) << 2;

    float4 xf[4];
    float4 wf;
#pragma unroll
    for (int i = 0; i < 4; i++)
        xf[i] = *reinterpret_cast<const float4*>(x + (xc + 8 * i) * NPIX + pt + xp);
    wf = *reinterpret_cast<const float4*>(W + (ot + lo) * 256 + lg);

    float acc[4][4];
#pragma unroll
    for (int j = 0; j < 4; j++)
#pragma unroll
        for (int i = 0; i < 4; i++) acc[j][i] = 0.f;

    for (int kt = 0; kt < 256; kt += 32) {
#pragma unroll
        for (int i = 0; i < 4; i++)
            *reinterpret_cast<float4*>(&Xs[xc + 8 * i][xp]) = xf[i];
        Wt[lg + 0][lo] = wf.x;
        Wt[lg + 1][lo] = wf.y;
        Wt[lg + 2][lo] = wf.z;
        Wt[lg + 3][lo] = wf.w;
        __syncthreads();
        if (kt + 32 < 256) {
#pragma unroll
            for (int i = 0; i < 4; i++)
                xf[i] = *reinterpret_cast<const float4*>(
                    x + (kt + 32 + xc + 8 * i) * NPIX + pt + xp);
            wf = *reinterpret_cast<const float4*>(W + (ot + lo) * 256 + kt + 32 + lg);
        }
#pragma unroll
        for (int kk = 0; kk < 32; kk++) {
            float4 a = *reinterpret_cast<const float4*>(&Xs[kk][pc << 2]);
            float av[4] = {a.x, a.y, a.z, a.w};
            float4 b4 = *reinterpret_cast<const float4*>(&Wt[kk][oc << 2]);
            float bv[4] = {b4.x, b4.y, b4.z, b4.w};
#pragma unroll
            for (int j = 0; j < 4; j++)
#pragma unroll
                for (int i = 0; i < 4; i++)
                    acc[j][i] = fmaf(bv[j], av[i], acc[j][i]);
        }
        __syncthreads();
    }

    if (mat < 2) {
#pragma unroll
        for (int j = 0; j < 4; j++) {
            const int o = ot + (oc << 2) + j;
            float4 r;
            r.x = 1.f / (1.f + __expf(-acc[j][0]));
            r.y = 1.f / (1.f + __expf(-acc[j][1]));
            r.z = 1.f / (1.f + __expf(-acc[j][2]));
            r.w = 1.f / (1.f + __expf(-acc[j][3]));
            *reinterpret_cast<float4*>(out + o * NPIX + pt + (pc << 2)) = r;
        }
    } else {
        float* scratch = &Xs[0][0];
        __syncthreads();
#pragma unroll
        for (int i = 0; i < 4; i++) {
            float ss = 0.f;
#pragma unroll
            for (int j = 0; j < 4; j++) ss += acc[j][i] * acc[j][i];
            scratch[oc * 128 + (pc << 2) + i] = ss;
        }
        __syncthreads();
        float scale[4];
#pragma unroll
        for (int i = 0; i < 4; i++) {
            float tot = 0.f;
#pragma unroll
            for (int g = 0; g < 8; g++) tot += scratch[g * 128 + (pc << 2) + i];
            scale[i] = 1.f / fmaxf(sqrtf(tot), 1e-12f);
        }
#pragma unroll
        for (int j = 0; j < 4; j++) {
            const int o = ot + (oc << 2) + j;
            float4 r;
            r.x = acc[j][0] * scale[0];
            r.y = acc[j][1] * scale[1];
            r.z = acc[j][2] * scale[2];
            r.w = acc[j][3] * scale[3];
            *reinterpret_cast<float4*>(out + o * NPIX + pt + (pc << 2)) = r;
        }
    }
}

// ---------------------------------------------------------------------------
// Kernel 2: fused integral-image + windowed contraction, 512 threads (8 waves).
// R9-EXACT revert (measured 71.5/71.6/71.8 us, VGPR 72, conflicts 0.68M).
// R12 (1-barrier dbuf) was neutral; R13 (y-major) regressed (VGPR 128,
// conflicts 4.6M). This x-major 2-barrier structure is the proven optimum.
// All register-array loops compile-time (R8 lesson); one-arg launch_bounds
// (R4 lesson: VGPR cliffs at 64/128 halve residency).
// ---------------------------------------------------------------------------
template <int PD>
__global__ __launch_bounds__(512) void attn_kernel(
    const float* __restrict__ q, const float* __restrict__ k,
    const float* __restrict__ v, float* __restrict__ num, float* __restrict__ nrm)
{
    const int f = blockIdx.x;          // 0..32 (32 == norm slot)
    const int head = blockIdx.y;       // 0..7
    const int dg = blockIdx.z;         // 0..(32/PD - 1)
    const bool isnorm = (f == 32);

    const float* __restrict__ kh = k + (head * 32 + dg * PD) * NPIX;
    const float* __restrict__ qh = q + (head * 32 + dg * PD) * NPIX;
    const float* __restrict__ vf = v + (head * 32 + (isnorm ? 0 : f)) * NPIX;

    __shared__ __align__(16) float Pt[65][132];   // 34,320 B
    __shared__ float csum[8][68];

    const int t = threadIdx.x;
    const int lane = t & 63;
    const int wv = t >> 6;             // 0..7

    // zero-init once; yp 0..31 (y<0) and Pt[0][*] (x=0) stay zero forever
    for (int i = t; i < 65 * 132; i += 512) (&Pt[0][0])[i] = 0.f;

    float vreg[8], kcur[8];
#pragma unroll
    for (int i = 0; i < 8; i++) {
        const int r = wv * 8 + i;
        vreg[i] = isnorm ? 1.f : vf[r * 64 + lane];
        kcur[i] = kh[r * 64 + lane];
    }

    float acc[3][8];
#pragma unroll
    for (int w = 0; w < 3; w++)
#pragma unroll
        for (int i = 0; i < 8; i++) acc[w][i] = 0.f;

    lds_barrier();                     // zero-init visible

    for (int dd = 0; dd < PD; dd++) {
        // prefetch q for THIS d (consumed in phase 4)
        float qv[8];
#pragma unroll
        for (int g = 0; g < 2; g++)
#pragma unroll
            for (int j = 0; j < 4; j++)
                qv[g * 4 + j] = qh[dd * NPIX + ((wv + 8 * g) * 4 + j) * 64 + lane];

        // phase 1: row iscans + in-register EXCLUSIVE column prefix
        float pv[8];
        float run = 0.f;
#pragma unroll
        for (int i = 0; i < 8; i++) {
            float rs = wave_iscan(kcur[i] * vreg[i]);
            pv[i] = run;               // P row (8*wv + i)
            run += rs;
        }
        if (dd + 1 < PD) {             // reload k for next d (covered by ph4)
#pragma unroll
            for (int i = 0; i < 8; i++)
                kcur[i] = kh[(dd + 1) * NPIX + (wv * 8 + i) * 64 + lane];
        }
        csum[wv][lane] = run;
        lds_barrier();                 // A: csum ready; fences prev phase-4
        float off = 0.f;
#pragma unroll
        for (int w2 = 0; w2 < 7; w2++) if (w2 < wv) off += csum[w2][lane];
#pragma unroll
        for (int i = 0; i < 8; i++) pv[i] += off;
#pragma unroll
        for (int s = 0; s < 2; s++) {
            float4 r4 = make_float4(pv[4 * s], pv[4 * s + 1], pv[4 * s + 2], pv[4 * s + 3]);
            *reinterpret_cast<float4*>(&Pt[lane + 1][32 + wv * 8 + 4 * s]) = r4;
        }
        if (wv == 7) {                 // row y=64 (yp 96) + replicate pad
            const float tot = off + run;
            const float4 p4 = make_float4(tot, tot, tot, tot);
#pragma unroll
            for (int s = 0; s < 8; s++)
                *reinterpret_cast<float4*>(&Pt[lane + 1][96 + 4 * s]) = p4;
        }
        lds_barrier();                 // B: P complete
        // phase 4: windowed box-diff contraction, float4 corner reads
#pragma unroll
        for (int g = 0; g < 2; g++) {
            const int y0 = (wv + 8 * g) * 4;
#pragma unroll
            for (int w = 0; w < 3; w++) {
                const int hw = 32 >> w;
                const int xlo = max(lane - hw, 0);
                const int xhi = min(lane + hw, 64);
                const int ylo = 32 + y0 - hw;
                const int yhi = 32 + y0 + hw;
                float4 A4 = *reinterpret_cast<const float4*>(&Pt[xhi][yhi]);
                float4 B4 = *reinterpret_cast<const float4*>(&Pt[xlo][yhi]);
                float4 C4, E4;
                if (y0 + 3 <= hw) {    // wave-uniform: whole quad in zero pad
                    C4 = make_float4(0.f, 0.f, 0.f, 0.f);
                    E4 = C4;
                } else {
                    C4 = *reinterpret_cast<const float4*>(&Pt[xhi][ylo]);
                    E4 = *reinterpret_cast<const float4*>(&Pt[xlo][ylo]);
                }
                acc[w][g * 4 + 0] = fmaf(qv[g * 4 + 0], (A4.x - B4.x) - (C4.x - E4.x), acc[w][g * 4 + 0]);
                acc[w][g * 4 + 1] = fmaf(qv[g * 4 + 1], (A4.y - B4.y) - (C4.y - E4.y), acc[w][g * 4 + 1]);
                acc[w][g * 4 + 2] = fmaf(qv[g * 4 + 2], (A4.z - B4.z) - (C4.z - E4.z), acc[w][g * 4 + 2]);
                acc[w][g * 4 + 3] = fmaf(qv[g * 4 + 3], (A4.w - B4.w) - (C4.w - E4.w), acc[w][g * 4 + 3]);
            }
        }
        // no trailing barrier: next iter's barrier A fences Pt rewrite
    }

    float* __restrict__ nout = num + (size_t)dg * CHSZ;
    float* __restrict__ rout = nrm + (size_t)dg * NRMSZ;
#pragma unroll
    for (int w = 0; w < 3; w++) {
#pragma unroll
        for (int g = 0; g < 2; g++) {
#pragma unroll
            for (int j = 0; j < 4; j++) {
                const int px = ((wv + 8 * g) * 4 + j) * 64 + lane;
                const float val = acc[w][g * 4 + j];
                if (isnorm) rout[(w * 8 + head) * NPIX + px] = val;
                else        nout[((w * 8 + head) * 32 + f) * NPIX + px] = val;
            }
        }
    }
}

// ---------------------------------------------------------------------------
// Kernel 3: final 1x1 conv partial; R14: 128px x 64out tiles, acc[8][4]
// (32 FMA per 3 b128 reads — +33% FMA/LDS-instr vs acc[4][4]'s 16/2).
// K-split z=3 (8 channels each), grid (32, 4, 3) = 384 blocks.
// NS partials summed AT LOAD into running registers (snv[4]) to keep
// VGPR ~80 (R4/R8 lessons: no cliffs, no runtime-indexed arrays).
// ---------------------------------------------------------------------------
template <int NS>
__global__ __launch_bounds__(256) void out_kernel(
    const float* __restrict__ num, const float* __restrict__ nrm,
    const float* __restrict__ Wout, float* __restrict__ obuf)
{
    const int pt = blockIdx.x * 128;
    const int ot = blockIdx.y * 64;
    const int kt0 = blockIdx.z * 8;
    __shared__ __align__(16) float As[32][132];
    __shared__ __align__(16) float Wt[32][68];   // [c][o]
    const int t = threadIdx.x;
    const int pc = t & 31;         // 32 pixel groups x 4 px
    const int oc = t >> 5;         // 8 output groups x 8 o
    const int xc = t >> 5;         // staging c rows xc + 8*i
    const int xp = (t & 31) << 2;
    const int lo = t & 63;         // W loader: o
    const int lc = (t >> 6) << 2;  // W loader: c bases lc, lc+16

    float4 snv[4], smv, wf[2];
#pragma unroll
    for (int i = 0; i < 4; i++) {
        snv[i] = *reinterpret_cast<const float4*>(
            num + (size_t)(kt0 * 32 + xc + 8 * i) * NPIX + pt + xp);
#pragma unroll
        for (int s = 1; s < NS; s++) {
            float4 v2 = *reinterpret_cast<const float4*>(
                num + (size_t)s * CHSZ + (size_t)(kt0 * 32 + xc + 8 * i) * NPIX + pt + xp);
            snv[i].x += v2.x; snv[i].y += v2.y; snv[i].z += v2.z; snv[i].w += v2.w;
        }
    }
    smv = *reinterpret_cast<const float4*>(nrm + kt0 * NPIX + pt + xp);
#pragma unroll
    for (int s = 1; s < NS; s++) {
        float4 v2 = *reinterpret_cast<const float4*>(
            nrm + (size_t)s * NRMSZ + kt0 * NPIX + pt + xp);
        smv.x += v2.x; smv.y += v2.y; smv.z += v2.z; smv.w += v2.w;
    }
    wf[0] = *reinterpret_cast<const float4*>(Wout + (ot + lo) * 768 + kt0 * 32 + lc);
    wf[1] = *reinterpret_cast<const float4*>(Wout + (ot + lo) * 768 + kt0 * 32 + lc + 16);

    float acc[8][4];
#pragma unroll
    for (int j = 0; j < 8; j++)
#pragma unroll
        for (int i = 0; i < 4; i++) acc[j][i] = 0.f;

    for (int kt = kt0; kt < kt0 + 8; kt++) {
        float4 rv;
        rv.x = 1.f / (smv.x + 1e-6f); rv.y = 1.f / (smv.y + 1e-6f);
        rv.z = 1.f / (smv.z + 1e-6f); rv.w = 1.f / (smv.w + 1e-6f);
#pragma unroll
        for (int i = 0; i < 4; i++) {
            float4 r;
            r.x = snv[i].x * rv.x; r.y = snv[i].y * rv.y;
            r.z = snv[i].z * rv.z; r.w = snv[i].w * rv.w;
            *reinterpret_cast<float4*>(&As[xc + 8 * i][xp]) = r;
        }
#pragma unroll
        for (int i = 0; i < 2; i++) {
            Wt[lc + 16 * i + 0][lo] = wf[i].x;
            Wt[lc + 16 * i + 1][lo] = wf[i].y;
            Wt[lc + 16 * i + 2][lo] = wf[i].z;
            Wt[lc + 16 * i + 3][lo] = wf[i].w;
        }
        __syncthreads();
        if (kt + 1 < kt0 + 8) {        // prefetch next channel tile (summed)
#pragma unroll
            for (int i = 0; i < 4; i++) {
                snv[i] = *reinterpret_cast<const float4*>(
                    num + (size_t)((kt + 1) * 32 + xc + 8 * i) * NPIX + pt + xp);
#pragma unroll
                for (int s = 1; s < NS; s++) {
                    float4 v2 = *reinterpret_cast<const float4*>(
                        num + (size_t)s * CHSZ +
                        (size_t)((kt + 1) * 32 + xc + 8 * i) * NPIX + pt + xp);
                    snv[i].x += v2.x; snv[i].y += v2.y;
                    snv[i].z += v2.z; snv[i].w += v2.w;
                }
            }
            smv = *reinterpret_cast<const float4*>(
                nrm + (kt + 1) * NPIX + pt + xp);
#pragma unroll
            for (int s = 1; s < NS; s++) {
                float4 v2 = *reinterpret_cast<const float4*>(
                    nrm + (size_t)s * NRMSZ + (kt + 1) * NPIX + pt + xp);
                smv.x += v2.x; smv.y += v2.y; smv.z += v2.z; smv.w += v2.w;
            }
            wf[0] = *reinterpret_cast<const float4*>(
                Wout + (ot + lo) * 768 + (kt + 1) * 32 + lc);
            wf[1] = *reinterpret_cast<const float4*>(
                Wout + (ot + lo) * 768 + (kt + 1) * 32 + lc + 16);
        }
#pragma unroll
        for (int kk = 0; kk < 32; kk++) {
            float4 a = *reinterpret_cast<const float4*>(&As[kk][pc << 2]);
            float av[4] = {a.x, a.y, a.z, a.w};
            float4 b0 = *reinterpret_cast<const float4*>(&Wt[kk][oc << 3]);
            float4 b1 = *reinterpret_cast<const float4*>(&Wt[kk][(oc << 3) + 4]);
            float bv[8] = {b0.x, b0.y, b0.z, b0.w, b1.x, b1.y, b1.z, b1.w};
#pragma unroll
            for (int j = 0; j < 8; j++)
#pragma unroll
                for (int i = 0; i < 4; i++)
                    acc[j][i] = fmaf(bv[j], av[i], acc[j][i]);
        }
        __syncthreads();
    }

    float* __restrict__ ob = obuf + (size_t)blockIdx.z * 1048576;
#pragma unroll
    for (int j = 0; j < 8; j++) {
        const int o = ot + (oc << 3) + j;
        float4 r;
        r.x = acc[j][0]; r.y = acc[j][1]; r.z = acc[j][2]; r.w = acc[j][3];
        *reinterpret_cast<float4*>(ob + o * NPIX + pt + (pc << 2)) = r;
    }
}

// ---------------------------------------------------------------------------
// Kernel 4: merge 3 K-split partials + bias. 1M floats, float4/thread.
// ---------------------------------------------------------------------------
__global__ __launch_bounds__(256) void kmerge_kernel(
    const float* __restrict__ obuf, const float* __restrict__ bout,
    float* __restrict__ out)
{
    const int i4 = (blockIdx.x * 256 + threadIdx.x) * 4;
    const float bb = bout[i4 >> 12];
    float4 a = *reinterpret_cast<const float4*>(obuf + i4);
    float4 b = *reinterpret_cast<const float4*>(obuf + 1048576 + i4);
    float4 c = *reinterpret_cast<const float4*>(obuf + 2097152 + i4);
    float4 r;
    r.x = a.x + b.x + c.x + bb;
    r.y = a.y + b.y + c.y + bb;
    r.z = a.z + b.z + c.z + bb;
    r.w = a.w + b.w + c.w + bb;
    *reinterpret_cast<float4*>(out + i4) = r;
}

extern "C" void kernel_launch(void* const* d_in, const int* in_sizes, int n_in,
                              void* d_out, int out_size, void* d_ws, size_t ws_size,
                              hipStream_t stream)
{
    const float* x    = (const float*)d_in[0];
    const float* Wq   = (const float*)d_in[1];
    const float* Wk   = (const float*)d_in[2];
    const float* Wv   = (const float*)d_in[3];
    const float* Wout = (const float*)d_in[4];
    const float* bout = (const float*)d_in[5];
    float* out = (float*)d_out;

    float* ws = (float*)d_ws;
    float* q   = ws;                  // 1,048,576 floats
    float* k   = ws + 1048576;
    float* v   = ws + 2097152;
    float* num = ws + 3145728;        // NS partials of CHSZ, then NS of NRMSZ
    float* obuf = ws;                 // 3 x 1,048,576 — aliases dead q/k/v
    const size_t fl = ws_size / 4;

    qkv_kernel<<<dim3(32, 8, 3), 256, 0, stream>>>(x, Wq, Wk, Wv, q, k, v);

    if (fl >= 3145728 + (size_t)4 * (CHSZ + NRMSZ)) {        // NS = 4
        float* nrm = num + (size_t)4 * CHSZ;
        attn_kernel<8><<<dim3(33, 8, 4), 512, 0, stream>>>(q, k, v, num, nrm);
        out_kernel<4><<<dim3(32, 4, 3), 256, 0, stream>>>(num, nrm, Wout, obuf);
    } else if (fl >= 3145728 + (size_t)2 * (CHSZ + NRMSZ)) { // NS = 2
        float* nrm = num + (size_t)2 * CHSZ;
        attn_kernel<16><<<dim3(33, 8, 2), 512, 0, stream>>>(q, k, v, num, nrm);
        out_kernel<2><<<dim3(32, 4, 3), 256, 0, stream>>>(num, nrm, Wout, obuf);
    } else {                                                 // NS = 1
        float* nrm = num + CHSZ;
        attn_kernel<32><<<dim3(33, 8, 1), 512, 0, stream>>>(q, k, v, num, nrm);
        out_kernel<1><<<dim3(32, 4, 3), 256, 0, stream>>>(num, nrm, Wout, obuf);
    }
    kmerge_kernel<<<dim3(1024), 256, 0, stream>>>(obuf, bout, out);
}

// Round 15
// 143.428 us; speedup vs baseline: 1.2496x; 1.0316x over previous
//
#include <hip/hip_runtime.h>
#include <math.h>

#define NPIX 4096
#define CHSZ 3145728   // one num partial: 24*32*4096 floats
#define NRMSZ 98304    // one nrm partial: 24*4096 floats

// ---------------------------------------------------------------------------
// DPP-based 64-lane inclusive scan (VALU only, no LDS traffic)
// ---------------------------------------------------------------------------
template <int CTRL, int RM>
__device__ __forceinline__ float dpp_add(float x) {
    int xi = __builtin_bit_cast(int, x);
    int sh = __builtin_amdgcn_update_dpp(0, xi, CTRL, RM, 0xf, false);
    return x + __builtin_bit_cast(float, sh);
}

__device__ __forceinline__ float wave_iscan(float x) {
    x = dpp_add<0x111, 0xf>(x);   // row_shr:1
    x = dpp_add<0x112, 0xf>(x);   // row_shr:2
    x = dpp_add<0x114, 0xf>(x);   // row_shr:4
    x = dpp_add<0x118, 0xf>(x);   // row_shr:8
    x = dpp_add<0x142, 0xa>(x);   // row_bcast:15 -> rows 1,3
    x = dpp_add<0x143, 0xc>(x);   // row_bcast:31 -> rows 2,3
    return x;
}

// LDS-only barrier: drain lgkm (ds ops) but leave global loads in flight.
__device__ __forceinline__ void lds_barrier() {
    asm volatile("s_waitcnt lgkmcnt(0)" ::: "memory");
    __builtin_amdgcn_s_barrier();
    __builtin_amdgcn_sched_barrier(0);
}

// ---------------------------------------------------------------------------
// Kernel 1: fused QKV 1x1-conv GEMM, 128px x 32out tiles + register prefetch
// (unchanged from R7/R9).
// ---------------------------------------------------------------------------
__global__ __launch_bounds__(256) void qkv_kernel(
    const float* __restrict__ x, const float* __restrict__ Wq,
    const float* __restrict__ Wk, const float* __restrict__ Wv,
    float* __restrict__ qo, float* __restrict__ ko, float* __restrict__ vo)
{
    const int pt = blockIdx.x * 128;
    const int ot = blockIdx.y * 32;
    const int mat = blockIdx.z;
    const float* __restrict__ W = (mat == 0) ? Wq : ((mat == 1) ? Wk : Wv);
    float* __restrict__ out = (mat == 0) ? qo : ((mat == 1) ? ko : vo);

    __shared__ __align__(16) float Xs[32][132];
    __shared__ __align__(16) float Wt[32][36];   // [c][o]

    const int t = threadIdx.x;
    const int pc = t & 31;
    const int oc = t >> 5;
    const int xc = t >> 5;
    const int xp = (t & 31) << 2;
    const int lo = t >> 3;
    const int lg = (t & 7) << 2;

    float4 xf[4];
    float4 wf;
#pragma unroll
    for (int i = 0; i < 4; i++)
        xf[i] = *reinterpret_cast<const float4*>(x + (xc + 8 * i) * NPIX + pt + xp);
    wf = *reinterpret_cast<const float4*>(W + (ot + lo) * 256 + lg);

    float acc[4][4];
#pragma unroll
    for (int j = 0; j < 4; j++)
#pragma unroll
        for (int i = 0; i < 4; i++) acc[j][i] = 0.f;

    for (int kt = 0; kt < 256; kt += 32) {
#pragma unroll
        for (int i = 0; i < 4; i++)
            *reinterpret_cast<float4*>(&Xs[xc + 8 * i][xp]) = xf[i];
        Wt[lg + 0][lo] = wf.x;
        Wt[lg + 1][lo] = wf.y;
        Wt[lg + 2][lo] = wf.z;
        Wt[lg + 3][lo] = wf.w;
        __syncthreads();
        if (kt + 32 < 256) {
#pragma unroll
            for (int i = 0; i < 4; i++)
                xf[i] = *reinterpret_cast<const float4*>(
                    x + (kt + 32 + xc + 8 * i) * NPIX + pt + xp);
            wf = *reinterpret_cast<const float4*>(W + (ot + lo) * 256 + kt + 32 + lg);
        }
#pragma unroll
        for (int kk = 0; kk < 32; kk++) {
            float4 a = *reinterpret_cast<const float4*>(&Xs[kk][pc << 2]);
            float av[4] = {a.x, a.y, a.z, a.w};
            float4 b4 = *reinterpret_cast<const float4*>(&Wt[kk][oc << 2]);
            float bv[4] = {b4.x, b4.y, b4.z, b4.w};
#pragma unroll
            for (int j = 0; j < 4; j++)
#pragma unroll
                for (int i = 0; i < 4; i++)
                    acc[j][i] = fmaf(bv[j], av[i], acc[j][i]);
        }
        __syncthreads();
    }

    if (mat < 2) {
#pragma unroll
        for (int j = 0; j < 4; j++) {
            const int o = ot + (oc << 2) + j;
            float4 r;
            r.x = 1.f / (1.f + __expf(-acc[j][0]));
            r.y = 1.f / (1.f + __expf(-acc[j][1]));
            r.z = 1.f / (1.f + __expf(-acc[j][2]));
            r.w = 1.f / (1.f + __expf(-acc[j][3]));
            *reinterpret_cast<float4*>(out + o * NPIX + pt + (pc << 2)) = r;
        }
    } else {
        float* scratch = &Xs[0][0];
        __syncthreads();
#pragma unroll
        for (int i = 0; i < 4; i++) {
            float ss = 0.f;
#pragma unroll
            for (int j = 0; j < 4; j++) ss += acc[j][i] * acc[j][i];
            scratch[oc * 128 + (pc << 2) + i] = ss;
        }
        __syncthreads();
        float scale[4];
#pragma unroll
        for (int i = 0; i < 4; i++) {
            float tot = 0.f;
#pragma unroll
            for (int g = 0; g < 8; g++) tot += scratch[g * 128 + (pc << 2) + i];
            scale[i] = 1.f / fmaxf(sqrtf(tot), 1e-12f);
        }
#pragma unroll
        for (int j = 0; j < 4; j++) {
            const int o = ot + (oc << 2) + j;
            float4 r;
            r.x = acc[j][0] * scale[0];
            r.y = acc[j][1] * scale[1];
            r.z = acc[j][2] * scale[2];
            r.w = acc[j][3] * scale[3];
            *reinterpret_cast<float4*>(out + o * NPIX + pt + (pc << 2)) = r;
        }
    }
}

// ---------------------------------------------------------------------------
// Kernel 2: fused integral-image + windowed contraction, 512 threads (8 waves).
// R9-EXACT (measured 71.5/71.6/71.8/71.7 us over four rounds, VGPR 72,
// conflicts 0.68M). R12 dbuf = neutral; R13 y-major = regression. Frozen.
// ---------------------------------------------------------------------------
template <int PD>
__global__ __launch_bounds__(512) void attn_kernel(
    const float* __restrict__ q, const float* __restrict__ k,
    const float* __restrict__ v, float* __restrict__ num, float* __restrict__ nrm)
{
    const int f = blockIdx.x;          // 0..32 (32 == norm slot)
    const int head = blockIdx.y;       // 0..7
    const int dg = blockIdx.z;         // 0..(32/PD - 1)
    const bool isnorm = (f == 32);

    const float* __restrict__ kh = k + (head * 32 + dg * PD) * NPIX;
    const float* __restrict__ qh = q + (head * 32 + dg * PD) * NPIX;
    const float* __restrict__ vf = v + (head * 32 + (isnorm ? 0 : f)) * NPIX;

    __shared__ __align__(16) float Pt[65][132];   // 34,320 B
    __shared__ float csum[8][68];

    const int t = threadIdx.x;
    const int lane = t & 63;
    const int wv = t >> 6;             // 0..7

    for (int i = t; i < 65 * 132; i += 512) (&Pt[0][0])[i] = 0.f;

    float vreg[8], kcur[8];
#pragma unroll
    for (int i = 0; i < 8; i++) {
        const int r = wv * 8 + i;
        vreg[i] = isnorm ? 1.f : vf[r * 64 + lane];
        kcur[i] = kh[r * 64 + lane];
    }

    float acc[3][8];
#pragma unroll
    for (int w = 0; w < 3; w++)
#pragma unroll
        for (int i = 0; i < 8; i++) acc[w][i] = 0.f;

    lds_barrier();                     // zero-init visible

    for (int dd = 0; dd < PD; dd++) {
        float qv[8];
#pragma unroll
        for (int g = 0; g < 2; g++)
#pragma unroll
            for (int j = 0; j < 4; j++)
                qv[g * 4 + j] = qh[dd * NPIX + ((wv + 8 * g) * 4 + j) * 64 + lane];

        float pv[8];
        float run = 0.f;
#pragma unroll
        for (int i = 0; i < 8; i++) {
            float rs = wave_iscan(kcur[i] * vreg[i]);
            pv[i] = run;
            run += rs;
        }
        if (dd + 1 < PD) {
#pragma unroll
            for (int i = 0; i < 8; i++)
                kcur[i] = kh[(dd + 1) * NPIX + (wv * 8 + i) * 64 + lane];
        }
        csum[wv][lane] = run;
        lds_barrier();                 // A: csum ready; fences prev phase-4
        float off = 0.f;
#pragma unroll
        for (int w2 = 0; w2 < 7; w2++) if (w2 < wv) off += csum[w2][lane];
#pragma unroll
        for (int i = 0; i < 8; i++) pv[i] += off;
#pragma unroll
        for (int s = 0; s < 2; s++) {
            float4 r4 = make_float4(pv[4 * s], pv[4 * s + 1], pv[4 * s + 2], pv[4 * s + 3]);
            *reinterpret_cast<float4*>(&Pt[lane + 1][32 + wv * 8 + 4 * s]) = r4;
        }
        if (wv == 7) {
            const float tot = off + run;
            const float4 p4 = make_float4(tot, tot, tot, tot);
#pragma unroll
            for (int s = 0; s < 8; s++)
                *reinterpret_cast<float4*>(&Pt[lane + 1][96 + 4 * s]) = p4;
        }
        lds_barrier();                 // B: P complete
#pragma unroll
        for (int g = 0; g < 2; g++) {
            const int y0 = (wv + 8 * g) * 4;
#pragma unroll
            for (int w = 0; w < 3; w++) {
                const int hw = 32 >> w;
                const int xlo = max(lane - hw, 0);
                const int xhi = min(lane + hw, 64);
                const int ylo = 32 + y0 - hw;
                const int yhi = 32 + y0 + hw;
                float4 A4 = *reinterpret_cast<const float4*>(&Pt[xhi][yhi]);
                float4 B4 = *reinterpret_cast<const float4*>(&Pt[xlo][yhi]);
                float4 C4, E4;
                if (y0 + 3 <= hw) {
                    C4 = make_float4(0.f, 0.f, 0.f, 0.f);
                    E4 = C4;
                } else {
                    C4 = *reinterpret_cast<const float4*>(&Pt[xhi][ylo]);
                    E4 = *reinterpret_cast<const float4*>(&Pt[xlo][ylo]);
                }
                acc[w][g * 4 + 0] = fmaf(qv[g * 4 + 0], (A4.x - B4.x) - (C4.x - E4.x), acc[w][g * 4 + 0]);
                acc[w][g * 4 + 1] = fmaf(qv[g * 4 + 1], (A4.y - B4.y) - (C4.y - E4.y), acc[w][g * 4 + 1]);
                acc[w][g * 4 + 2] = fmaf(qv[g * 4 + 2], (A4.z - B4.z) - (C4.z - E4.z), acc[w][g * 4 + 2]);
                acc[w][g * 4 + 3] = fmaf(qv[g * 4 + 3], (A4.w - B4.w) - (C4.w - E4.w), acc[w][g * 4 + 3]);
            }
        }
    }

    float* __restrict__ nout = num + (size_t)dg * CHSZ;
    float* __restrict__ rout = nrm + (size_t)dg * NRMSZ;
#pragma unroll
    for (int w = 0; w < 3; w++) {
#pragma unroll
        for (int g = 0; g < 2; g++) {
#pragma unroll
            for (int j = 0; j < 4; j++) {
                const int px = ((wv + 8 * g) * 4 + j) * 64 + lane;
                const float val = acc[w][g * 4 + j];
                if (isnorm) rout[(w * 8 + head) * NPIX + px] = val;
                else        nout[((w * 8 + head) * 32 + f) * NPIX + px] = val;
            }
        }
    }
}

// ---------------------------------------------------------------------------
// Kernel 3: final 1x1 conv partial; R11-EXACT tile (64px x 64out, acc[4][4],
// 256 thr) but K-split KS (24/KS channels per block), grid (64, 4, KS).
// KS=4 doubles resident blocks/CU (2 -> 4) at identical LDS work — R14 showed
// TLP, not traffic, is out's binding constraint alongside the LDS pipe.
// Partial z<3 -> obufA + z*1M (dead q/k/v); z==3 -> obufB (workspace tail).
// ---------------------------------------------------------------------------
template <int NS, int KS>
__global__ __launch_bounds__(256) void out_kernel(
    const float* __restrict__ num, const float* __restrict__ nrm,
    const float* __restrict__ Wout, float* __restrict__ obufA,
    float* __restrict__ obufB)
{
    const int pt = blockIdx.x * 64;
    const int ot = blockIdx.y * 64;
    constexpr int KC = 24 / KS;
    const int kt0 = blockIdx.z * KC;
    __shared__ __align__(16) float As[32][68];
    __shared__ __align__(16) float Wt[32][68];   // [c][o]
    const int t = threadIdx.x;
    const int pc = t & 15;
    const int oc = t >> 4;
    const int xc = t >> 4;
    const int xp = (t & 15) << 2;
    const int lo = t & 63;
    const int lc = (t >> 6) << 2;

    float4 nv[NS][2], mv[NS], wf[2];
#pragma unroll
    for (int s = 0; s < NS; s++) {
#pragma unroll
        for (int i = 0; i < 2; i++)
            nv[s][i] = *reinterpret_cast<const float4*>(
                num + (size_t)s * CHSZ + (size_t)(kt0 * 32 + xc + 16 * i) * NPIX + pt + xp);
        mv[s] = *reinterpret_cast<const float4*>(
            nrm + (size_t)s * NRMSZ + kt0 * NPIX + pt + xp);
    }
    wf[0] = *reinterpret_cast<const float4*>(Wout + (ot + lo) * 768 + kt0 * 32 + lc);
    wf[1] = *reinterpret_cast<const float4*>(Wout + (ot + lo) * 768 + kt0 * 32 + lc + 16);

    float acc[4][4];
#pragma unroll
    for (int j = 0; j < 4; j++)
#pragma unroll
        for (int i = 0; i < 4; i++) acc[j][i] = 0.f;

    for (int kt = kt0; kt < kt0 + KC; kt++) {
        float4 ms = mv[0];
#pragma unroll
        for (int s = 1; s < NS; s++) {
            ms.x += mv[s].x; ms.y += mv[s].y; ms.z += mv[s].z; ms.w += mv[s].w;
        }
        float4 rv;
        rv.x = 1.f / (ms.x + 1e-6f); rv.y = 1.f / (ms.y + 1e-6f);
        rv.z = 1.f / (ms.z + 1e-6f); rv.w = 1.f / (ms.w + 1e-6f);
#pragma unroll
        for (int i = 0; i < 2; i++) {
            float4 r = nv[0][i];
#pragma unroll
            for (int s = 1; s < NS; s++) {
                r.x += nv[s][i].x; r.y += nv[s][i].y;
                r.z += nv[s][i].z; r.w += nv[s][i].w;
            }
            r.x *= rv.x; r.y *= rv.y; r.z *= rv.z; r.w *= rv.w;
            *reinterpret_cast<float4*>(&As[xc + 16 * i][xp]) = r;
        }
#pragma unroll
        for (int i = 0; i < 2; i++) {
            Wt[lc + 16 * i + 0][lo] = wf[i].x;
            Wt[lc + 16 * i + 1][lo] = wf[i].y;
            Wt[lc + 16 * i + 2][lo] = wf[i].z;
            Wt[lc + 16 * i + 3][lo] = wf[i].w;
        }
        __syncthreads();
        if (kt + 1 < kt0 + KC) {
#pragma unroll
            for (int s = 0; s < NS; s++) {
#pragma unroll
                for (int i = 0; i < 2; i++)
                    nv[s][i] = *reinterpret_cast<const float4*>(
                        num + (size_t)s * CHSZ +
                        (size_t)((kt + 1) * 32 + xc + 16 * i) * NPIX + pt + xp);
                mv[s] = *reinterpret_cast<const float4*>(
                    nrm + (size_t)s * NRMSZ + (kt + 1) * NPIX + pt + xp);
            }
            wf[0] = *reinterpret_cast<const float4*>(
                Wout + (ot + lo) * 768 + (kt + 1) * 32 + lc);
            wf[1] = *reinterpret_cast<const float4*>(
                Wout + (ot + lo) * 768 + (kt + 1) * 32 + lc + 16);
        }
#pragma unroll
        for (int kk = 0; kk < 32; kk++) {
            float4 a = *reinterpret_cast<const float4*>(&As[kk][pc << 2]);
            float av[4] = {a.x, a.y, a.z, a.w};
            float4 b4 = *reinterpret_cast<const float4*>(&Wt[kk][oc << 2]);
            float bv[4] = {b4.x, b4.y, b4.z, b4.w};
#pragma unroll
            for (int j = 0; j < 4; j++)
#pragma unroll
                for (int i = 0; i < 4; i++)
                    acc[j][i] = fmaf(bv[j], av[i], acc[j][i]);
        }
        __syncthreads();
    }

    float* __restrict__ ob = (KS == 2 || blockIdx.z < 3)
        ? (obufA + (size_t)blockIdx.z * 1048576) : obufB;
#pragma unroll
    for (int j = 0; j < 4; j++) {
        const int o = ot + (oc << 2) + j;
        float4 r;
        r.x = acc[j][0]; r.y = acc[j][1]; r.z = acc[j][2]; r.w = acc[j][3];
        *reinterpret_cast<float4*>(ob + o * NPIX + pt + (pc << 2)) = r;
    }
}

// ---------------------------------------------------------------------------
// Kernel 4: merge KS K-split partials + bias. 1M floats, float4/thread.
// ---------------------------------------------------------------------------
template <int KS>
__global__ __launch_bounds__(256) void kmerge_kernel(
    const float* __restrict__ obufA, const float* __restrict__ obufB,
    const float* __restrict__ bout, float* __restrict__ out)
{
    const int i4 = (blockIdx.x * 256 + threadIdx.x) * 4;
    const float bb = bout[i4 >> 12];
    float4 a = *reinterpret_cast<const float4*>(obufA + i4);
    float4 b = *reinterpret_cast<const float4*>(obufA + 1048576 + i4);
    float rx = a.x + b.x, ry = a.y + b.y, rz = a.z + b.z, rw = a.w + b.w;
    if (KS == 4) {
        float4 c = *reinterpret_cast<const float4*>(obufA + 2097152 + i4);
        float4 d = *reinterpret_cast<const float4*>(obufB + i4);
        rx += c.x + d.x; ry += c.y + d.y; rz += c.z + d.z; rw += c.w + d.w;
    }
    float4 r = make_float4(rx + bb, ry + bb, rz + bb, rw + bb);
    *reinterpret_cast<float4*>(out + i4) = r;
}

extern "C" void kernel_launch(void* const* d_in, const int* in_sizes, int n_in,
                              void* d_out, int out_size, void* d_ws, size_t ws_size,
                              hipStream_t stream)
{
    const float* x    = (const float*)d_in[0];
    const float* Wq   = (const float*)d_in[1];
    const float* Wk   = (const float*)d_in[2];
    const float* Wv   = (const float*)d_in[3];
    const float* Wout = (const float*)d_in[4];
    const float* bout = (const float*)d_in[5];
    float* out = (float*)d_out;

    float* ws = (float*)d_ws;
    float* q   = ws;                  // 1,048,576 floats
    float* k   = ws + 1048576;
    float* v   = ws + 2097152;
    float* num = ws + 3145728;        // NS partials of CHSZ, then NS of NRMSZ
    float* obufA = ws;                // 3 x 1M — aliases dead q/k/v
    const size_t fl = ws_size / 4;

    const size_t need_ns4 = 3145728 + (size_t)4 * (CHSZ + NRMSZ);   // 16121856
    const size_t need_ks4 = need_ns4 + 1048576;                      // 17170432

    qkv_kernel<<<dim3(32, 8, 3), 256, 0, stream>>>(x, Wq, Wk, Wv, q, k, v);

    if (fl >= need_ks4) {                    // NS = 4, KS = 4
        float* nrm = num + (size_t)4 * CHSZ;
        float* obufB = ws + need_ns4;        // workspace tail, 1M floats
        attn_kernel<8><<<dim3(33, 8, 4), 512, 0, stream>>>(q, k, v, num, nrm);
        out_kernel<4, 4><<<dim3(64, 4, 4), 256, 0, stream>>>(num, nrm, Wout, obufA, obufB);
        kmerge_kernel<4><<<dim3(1024), 256, 0, stream>>>(obufA, obufB, bout, out);
    } else if (fl >= need_ns4) {             // NS = 4, KS = 2 (R11-exact path)
        float* nrm = num + (size_t)4 * CHSZ;
        attn_kernel<8><<<dim3(33, 8, 4), 512, 0, stream>>>(q, k, v, num, nrm);
        out_kernel<4, 2><<<dim3(64, 4, 2), 256, 0, stream>>>(num, nrm, Wout, obufA, obufA);
        kmerge_kernel<2><<<dim3(1024), 256, 0, stream>>>(obufA, obufA, bout, out);
    } else if (fl >= 3145728 + (size_t)2 * (CHSZ + NRMSZ)) {  // NS = 2
        float* nrm = num + (size_t)2 * CHSZ;
        attn_kernel<16><<<dim3(33, 8, 2), 512, 0, stream>>>(q, k, v, num, nrm);
        out_kernel<2, 2><<<dim3(64, 4, 2), 256, 0, stream>>>(num, nrm, Wout, obufA, obufA);
        kmerge_kernel<2><<<dim3(1024), 256, 0, stream>>>(obufA, obufA, bout, out);
    } else {                                 // NS = 1
        float* nrm = num + CHSZ;
        attn_kernel<32><<<dim3(33, 8, 1), 512, 0, stream>>>(q, k, v, num, nrm);
        out_kernel<1, 2><<<dim3(64, 4, 2), 256, 0, stream>>>(num, nrm, Wout, obufA, obufA);
        kmerge_kernel<2><<<dim3(1024), 256, 0, stream>>>(obufA, obufA, bout, out);
    }
}

// Round 16
// 141.682 us; speedup vs baseline: 1.2650x; 1.0123x over previous
//
#include <hip/hip_runtime.h>
#include <math.h>

#define NPIX 4096
#define CHSZ 3145728   // one num partial: 24*32*4096 floats
#define NRMSZ 98304    // one nrm partial: 24*4096 floats

// ---------------------------------------------------------------------------
// DPP-based 64-lane inclusive scan (VALU only, no LDS traffic)
// ---------------------------------------------------------------------------
template <int CTRL, int RM>
__device__ __forceinline__ float dpp_add(float x) {
    int xi = __builtin_bit_cast(int, x);
    int sh = __builtin_amdgcn_update_dpp(0, xi, CTRL, RM, 0xf, false);
    return x + __builtin_bit_cast(float, sh);
}

__device__ __forceinline__ float wave_iscan(float x) {
    x = dpp_add<0x111, 0xf>(x);   // row_shr:1
    x = dpp_add<0x112, 0xf>(x);   // row_shr:2
    x = dpp_add<0x114, 0xf>(x);   // row_shr:4
    x = dpp_add<0x118, 0xf>(x);   // row_shr:8
    x = dpp_add<0x142, 0xa>(x);   // row_bcast:15 -> rows 1,3
    x = dpp_add<0x143, 0xc>(x);   // row_bcast:31 -> rows 2,3
    return x;
}

// LDS-only barrier: drain lgkm (ds ops) but leave global loads in flight.
__device__ __forceinline__ void lds_barrier() {
    asm volatile("s_waitcnt lgkmcnt(0)" ::: "memory");
    __builtin_amdgcn_s_barrier();
    __builtin_amdgcn_sched_barrier(0);
}

// ---------------------------------------------------------------------------
// Kernel 1: fused QKV 1x1-conv GEMM, 128px x 32out tiles + register prefetch
// (frozen since R7; ~28 us, LDS-pipe-bound at 3 blocks/CU).
// ---------------------------------------------------------------------------
__global__ __launch_bounds__(256) void qkv_kernel(
    const float* __restrict__ x, const float* __restrict__ Wq,
    const float* __restrict__ Wk, const float* __restrict__ Wv,
    float* __restrict__ qo, float* __restrict__ ko, float* __restrict__ vo)
{
    const int pt = blockIdx.x * 128;
    const int ot = blockIdx.y * 32;
    const int mat = blockIdx.z;
    const float* __restrict__ W = (mat == 0) ? Wq : ((mat == 1) ? Wk : Wv);
    float* __restrict__ out = (mat == 0) ? qo : ((mat == 1) ? ko : vo);

    __shared__ __align__(16) float Xs[32][132];
    __shared__ __align__(16) float Wt[32][36];   // [c][o]

    const int t = threadIdx.x;
    const int pc = t & 31;
    const int oc = t >> 5;
    const int xc = t >> 5;
    const int xp = (t & 31) << 2;
    const int lo = t >> 3;
    const int lg = (t & 7) << 2;

    float4 xf[4];
    float4 wf;
#pragma unroll
    for (int i = 0; i < 4; i++)
        xf[i] = *reinterpret_cast<const float4*>(x + (xc + 8 * i) * NPIX + pt + xp);
    wf = *reinterpret_cast<const float4*>(W + (ot + lo) * 256 + lg);

    float acc[4][4];
#pragma unroll
    for (int j = 0; j < 4; j++)
#pragma unroll
        for (int i = 0; i < 4; i++) acc[j][i] = 0.f;

    for (int kt = 0; kt < 256; kt += 32) {
#pragma unroll
        for (int i = 0; i < 4; i++)
            *reinterpret_cast<float4*>(&Xs[xc + 8 * i][xp]) = xf[i];
        Wt[lg + 0][lo] = wf.x;
        Wt[lg + 1][lo] = wf.y;
        Wt[lg + 2][lo] = wf.z;
        Wt[lg + 3][lo] = wf.w;
        __syncthreads();
        if (kt + 32 < 256) {
#pragma unroll
            for (int i = 0; i < 4; i++)
                xf[i] = *reinterpret_cast<const float4*>(
                    x + (kt + 32 + xc + 8 * i) * NPIX + pt + xp);
            wf = *reinterpret_cast<const float4*>(W + (ot + lo) * 256 + kt + 32 + lg);
        }
#pragma unroll
        for (int kk = 0; kk < 32; kk++) {
            float4 a = *reinterpret_cast<const float4*>(&Xs[kk][pc << 2]);
            float av[4] = {a.x, a.y, a.z, a.w};
            float4 b4 = *reinterpret_cast<const float4*>(&Wt[kk][oc << 2]);
            float bv[4] = {b4.x, b4.y, b4.z, b4.w};
#pragma unroll
            for (int j = 0; j < 4; j++)
#pragma unroll
                for (int i = 0; i < 4; i++)
                    acc[j][i] = fmaf(bv[j], av[i], acc[j][i]);
        }
        __syncthreads();
    }

    if (mat < 2) {
#pragma unroll
        for (int j = 0; j < 4; j++) {
            const int o = ot + (oc << 2) + j;
            float4 r;
            r.x = 1.f / (1.f + __expf(-acc[j][0]));
            r.y = 1.f / (1.f + __expf(-acc[j][1]));
            r.z = 1.f / (1.f + __expf(-acc[j][2]));
            r.w = 1.f / (1.f + __expf(-acc[j][3]));
            *reinterpret_cast<float4*>(out + o * NPIX + pt + (pc << 2)) = r;
        }
    } else {
        float* scratch = &Xs[0][0];
        __syncthreads();
#pragma unroll
        for (int i = 0; i < 4; i++) {
            float ss = 0.f;
#pragma unroll
            for (int j = 0; j < 4; j++) ss += acc[j][i] * acc[j][i];
            scratch[oc * 128 + (pc << 2) + i] = ss;
        }
        __syncthreads();
        float scale[4];
#pragma unroll
        for (int i = 0; i < 4; i++) {
            float tot = 0.f;
#pragma unroll
            for (int g = 0; g < 8; g++) tot += scratch[g * 128 + (pc << 2) + i];
            scale[i] = 1.f / fmaxf(sqrtf(tot), 1e-12f);
        }
#pragma unroll
        for (int j = 0; j < 4; j++) {
            const int o = ot + (oc << 2) + j;
            float4 r;
            r.x = acc[j][0] * scale[0];
            r.y = acc[j][1] * scale[1];
            r.z = acc[j][2] * scale[2];
            r.w = acc[j][3] * scale[3];
            *reinterpret_cast<float4*>(out + o * NPIX + pt + (pc << 2)) = r;
        }
    }
}

// ---------------------------------------------------------------------------
// Kernel 2: fused integral-image + windowed contraction, 512 threads (8 waves).
// R9-EXACT (measured 71.5/71.6/71.8/71.7/72.0 us over five rounds, VGPR 72,
// conflicts 0.68M). R12 dbuf = neutral; R13 y-major = regression. FROZEN.
// ---------------------------------------------------------------------------
template <int PD>
__global__ __launch_bounds__(512) void attn_kernel(
    const float* __restrict__ q, const float* __restrict__ k,
    const float* __restrict__ v, float* __restrict__ num, float* __restrict__ nrm)
{
    const int f = blockIdx.x;          // 0..32 (32 == norm slot)
    const int head = blockIdx.y;       // 0..7
    const int dg = blockIdx.z;         // 0..(32/PD - 1)
    const bool isnorm = (f == 32);

    const float* __restrict__ kh = k + (head * 32 + dg * PD) * NPIX;
    const float* __restrict__ qh = q + (head * 32 + dg * PD) * NPIX;
    const float* __restrict__ vf = v + (head * 32 + (isnorm ? 0 : f)) * NPIX;

    __shared__ __align__(16) float Pt[65][132];   // 34,320 B
    __shared__ float csum[8][68];

    const int t = threadIdx.x;
    const int lane = t & 63;
    const int wv = t >> 6;             // 0..7

    for (int i = t; i < 65 * 132; i += 512) (&Pt[0][0])[i] = 0.f;

    float vreg[8], kcur[8];
#pragma unroll
    for (int i = 0; i < 8; i++) {
        const int r = wv * 8 + i;
        vreg[i] = isnorm ? 1.f : vf[r * 64 + lane];
        kcur[i] = kh[r * 64 + lane];
    }

    float acc[3][8];
#pragma unroll
    for (int w = 0; w < 3; w++)
#pragma unroll
        for (int i = 0; i < 8; i++) acc[w][i] = 0.f;

    lds_barrier();                     // zero-init visible

    for (int dd = 0; dd < PD; dd++) {
        float qv[8];
#pragma unroll
        for (int g = 0; g < 2; g++)
#pragma unroll
            for (int j = 0; j < 4; j++)
                qv[g * 4 + j] = qh[dd * NPIX + ((wv + 8 * g) * 4 + j) * 64 + lane];

        float pv[8];
        float run = 0.f;
#pragma unroll
        for (int i = 0; i < 8; i++) {
            float rs = wave_iscan(kcur[i] * vreg[i]);
            pv[i] = run;
            run += rs;
        }
        if (dd + 1 < PD) {
#pragma unroll
            for (int i = 0; i < 8; i++)
                kcur[i] = kh[(dd + 1) * NPIX + (wv * 8 + i) * 64 + lane];
        }
        csum[wv][lane] = run;
        lds_barrier();                 // A: csum ready; fences prev phase-4
        float off = 0.f;
#pragma unroll
        for (int w2 = 0; w2 < 7; w2++) if (w2 < wv) off += csum[w2][lane];
#pragma unroll
        for (int i = 0; i < 8; i++) pv[i] += off;
#pragma unroll
        for (int s = 0; s < 2; s++) {
            float4 r4 = make_float4(pv[4 * s], pv[4 * s + 1], pv[4 * s + 2], pv[4 * s + 3]);
            *reinterpret_cast<float4*>(&Pt[lane + 1][32 + wv * 8 + 4 * s]) = r4;
        }
        if (wv == 7) {
            const float tot = off + run;
            const float4 p4 = make_float4(tot, tot, tot, tot);
#pragma unroll
            for (int s = 0; s < 8; s++)
                *reinterpret_cast<float4*>(&Pt[lane + 1][96 + 4 * s]) = p4;
        }
        lds_barrier();                 // B: P complete
#pragma unroll
        for (int g = 0; g < 2; g++) {
            const int y0 = (wv + 8 * g) * 4;
#pragma unroll
            for (int w = 0; w < 3; w++) {
                const int hw = 32 >> w;
                const int xlo = max(lane - hw, 0);
                const int xhi = min(lane + hw, 64);
                const int ylo = 32 + y0 - hw;
                const int yhi = 32 + y0 + hw;
                float4 A4 = *reinterpret_cast<const float4*>(&Pt[xhi][yhi]);
                float4 B4 = *reinterpret_cast<const float4*>(&Pt[xlo][yhi]);
                float4 C4, E4;
                if (y0 + 3 <= hw) {
                    C4 = make_float4(0.f, 0.f, 0.f, 0.f);
                    E4 = C4;
                } else {
                    C4 = *reinterpret_cast<const float4*>(&Pt[xhi][ylo]);
                    E4 = *reinterpret_cast<const float4*>(&Pt[xlo][ylo]);
                }
                acc[w][g * 4 + 0] = fmaf(qv[g * 4 + 0], (A4.x - B4.x) - (C4.x - E4.x), acc[w][g * 4 + 0]);
                acc[w][g * 4 + 1] = fmaf(qv[g * 4 + 1], (A4.y - B4.y) - (C4.y - E4.y), acc[w][g * 4 + 1]);
                acc[w][g * 4 + 2] = fmaf(qv[g * 4 + 2], (A4.z - B4.z) - (C4.z - E4.z), acc[w][g * 4 + 2]);
                acc[w][g * 4 + 3] = fmaf(qv[g * 4 + 3], (A4.w - B4.w) - (C4.w - E4.w), acc[w][g * 4 + 3]);
            }
        }
    }

    float* __restrict__ nout = num + (size_t)dg * CHSZ;
    float* __restrict__ rout = nrm + (size_t)dg * NRMSZ;
#pragma unroll
    for (int w = 0; w < 3; w++) {
#pragma unroll
        for (int g = 0; g < 2; g++) {
#pragma unroll
            for (int j = 0; j < 4; j++) {
                const int px = ((wv + 8 * g) * 4 + j) * 64 + lane;
                const float val = acc[w][g * 4 + j];
                if (isnorm) rout[(w * 8 + head) * NPIX + px] = val;
                else        nout[((w * 8 + head) * 32 + f) * NPIX + px] = val;
            }
        }
    }
}

// ---------------------------------------------------------------------------
// Kernel 3: final 1x1 conv partial; R11-EXACT (measured-best): 64px x 64out,
// acc[4][4], 256 thr, K-split 2 (12 channels each), grid (64, 4, 2).
// Evidence: traffic/4 no effect (R10), LDS/2 -10us (R11), ratio+33% at
// 1.5 blk/CU +6us (R14), TLP x2 neutral (R15) -> this is the floor config.
// ---------------------------------------------------------------------------
template <int NS>
__global__ __launch_bounds__(256) void out_kernel(
    const float* __restrict__ num, const float* __restrict__ nrm,
    const float* __restrict__ Wout, float* __restrict__ obuf)
{
    const int pt = blockIdx.x * 64;
    const int ot = blockIdx.y * 64;
    const int kt0 = blockIdx.z * 12;
    __shared__ __align__(16) float As[32][68];
    __shared__ __align__(16) float Wt[32][68];   // [c][o]
    const int t = threadIdx.x;
    const int pc = t & 15;
    const int oc = t >> 4;
    const int xc = t >> 4;
    const int xp = (t & 15) << 2;
    const int lo = t & 63;
    const int lc = (t >> 6) << 2;

    float4 nv[NS][2], mv[NS], wf[2];
#pragma unroll
    for (int s = 0; s < NS; s++) {
#pragma unroll
        for (int i = 0; i < 2; i++)
            nv[s][i] = *reinterpret_cast<const float4*>(
                num + (size_t)s * CHSZ + (size_t)(kt0 * 32 + xc + 16 * i) * NPIX + pt + xp);
        mv[s] = *reinterpret_cast<const float4*>(
            nrm + (size_t)s * NRMSZ + kt0 * NPIX + pt + xp);
    }
    wf[0] = *reinterpret_cast<const float4*>(Wout + (ot + lo) * 768 + kt0 * 32 + lc);
    wf[1] = *reinterpret_cast<const float4*>(Wout + (ot + lo) * 768 + kt0 * 32 + lc + 16);

    float acc[4][4];
#pragma unroll
    for (int j = 0; j < 4; j++)
#pragma unroll
        for (int i = 0; i < 4; i++) acc[j][i] = 0.f;

    for (int kt = kt0; kt < kt0 + 12; kt++) {
        float4 ms = mv[0];
#pragma unroll
        for (int s = 1; s < NS; s++) {
            ms.x += mv[s].x; ms.y += mv[s].y; ms.z += mv[s].z; ms.w += mv[s].w;
        }
        float4 rv;
        rv.x = 1.f / (ms.x + 1e-6f); rv.y = 1.f / (ms.y + 1e-6f);
        rv.z = 1.f / (ms.z + 1e-6f); rv.w = 1.f / (ms.w + 1e-6f);
#pragma unroll
        for (int i = 0; i < 2; i++) {
            float4 r = nv[0][i];
#pragma unroll
            for (int s = 1; s < NS; s++) {
                r.x += nv[s][i].x; r.y += nv[s][i].y;
                r.z += nv[s][i].z; r.w += nv[s][i].w;
            }
            r.x *= rv.x; r.y *= rv.y; r.z *= rv.z; r.w *= rv.w;
            *reinterpret_cast<float4*>(&As[xc + 16 * i][xp]) = r;
        }
#pragma unroll
        for (int i = 0; i < 2; i++) {
            Wt[lc + 16 * i + 0][lo] = wf[i].x;
            Wt[lc + 16 * i + 1][lo] = wf[i].y;
            Wt[lc + 16 * i + 2][lo] = wf[i].z;
            Wt[lc + 16 * i + 3][lo] = wf[i].w;
        }
        __syncthreads();
        if (kt + 1 < kt0 + 12) {
#pragma unroll
            for (int s = 0; s < NS; s++) {
#pragma unroll
                for (int i = 0; i < 2; i++)
                    nv[s][i] = *reinterpret_cast<const float4*>(
                        num + (size_t)s * CHSZ +
                        (size_t)((kt + 1) * 32 + xc + 16 * i) * NPIX + pt + xp);
                mv[s] = *reinterpret_cast<const float4*>(
                    nrm + (size_t)s * NRMSZ + (kt + 1) * NPIX + pt + xp);
            }
            wf[0] = *reinterpret_cast<const float4*>(
                Wout + (ot + lo) * 768 + (kt + 1) * 32 + lc);
            wf[1] = *reinterpret_cast<const float4*>(
                Wout + (ot + lo) * 768 + (kt + 1) * 32 + lc + 16);
        }
#pragma unroll
        for (int kk = 0; kk < 32; kk++) {
            float4 a = *reinterpret_cast<const float4*>(&As[kk][pc << 2]);
            float av[4] = {a.x, a.y, a.z, a.w};
            float4 b4 = *reinterpret_cast<const float4*>(&Wt[kk][oc << 2]);
            float bv[4] = {b4.x, b4.y, b4.z, b4.w};
#pragma unroll
            for (int j = 0; j < 4; j++)
#pragma unroll
                for (int i = 0; i < 4; i++)
                    acc[j][i] = fmaf(bv[j], av[i], acc[j][i]);
        }
        __syncthreads();
    }

    float* __restrict__ ob = obuf + (size_t)blockIdx.z * 1048576;
#pragma unroll
    for (int j = 0; j < 4; j++) {
        const int o = ot + (oc << 2) + j;
        float4 r;
        r.x = acc[j][0]; r.y = acc[j][1]; r.z = acc[j][2]; r.w = acc[j][3];
        *reinterpret_cast<float4*>(ob + o * NPIX + pt + (pc << 2)) = r;
    }
}

// ---------------------------------------------------------------------------
// Kernel 4: merge 2 K-split partials + bias. 1M floats, float4/thread.
// ---------------------------------------------------------------------------
__global__ __launch_bounds__(256) void kmerge_kernel(
    const float* __restrict__ obuf, const float* __restrict__ bout,
    float* __restrict__ out)
{
    const int i4 = (blockIdx.x * 256 + threadIdx.x) * 4;
    const float bb = bout[i4 >> 12];
    float4 a = *reinterpret_cast<const float4*>(obuf + i4);
    float4 b = *reinterpret_cast<const float4*>(obuf + 1048576 + i4);
    float4 r;
    r.x = a.x + b.x + bb;
    r.y = a.y + b.y + bb;
    r.z = a.z + b.z + bb;
    r.w = a.w + b.w + bb;
    *reinterpret_cast<float4*>(out + i4) = r;
}

extern "C" void kernel_launch(void* const* d_in, const int* in_sizes, int n_in,
                              void* d_out, int out_size, void* d_ws, size_t ws_size,
                              hipStream_t stream)
{
    const float* x    = (const float*)d_in[0];
    const float* Wq   = (const float*)d_in[1];
    const float* Wk   = (const float*)d_in[2];
    const float* Wv   = (const float*)d_in[3];
    const float* Wout = (const float*)d_in[4];
    const float* bout = (const float*)d_in[5];
    float* out = (float*)d_out;

    float* ws = (float*)d_ws;
    float* q   = ws;                  // 1,048,576 floats
    float* k   = ws + 1048576;
    float* v   = ws + 2097152;
    float* num = ws + 3145728;        // NS partials of CHSZ, then NS of NRMSZ
    float* obuf = ws;                 // 2 x 1M — aliases dead q/k
    const size_t fl = ws_size / 4;

    qkv_kernel<<<dim3(32, 8, 3), 256, 0, stream>>>(x, Wq, Wk, Wv, q, k, v);

    if (fl >= 3145728 + (size_t)4 * (CHSZ + NRMSZ)) {        // NS = 4
        float* nrm = num + (size_t)4 * CHSZ;
        attn_kernel<8><<<dim3(33, 8, 4), 512, 0, stream>>>(q, k, v, num, nrm);
        out_kernel<4><<<dim3(64, 4, 2), 256, 0, stream>>>(num, nrm, Wout, obuf);
    } else if (fl >= 3145728 + (size_t)2 * (CHSZ + NRMSZ)) { // NS = 2
        float* nrm = num + (size_t)2 * CHSZ;
        attn_kernel<16><<<dim3(33, 8, 2), 512, 0, stream>>>(q, k, v, num, nrm);
        out_kernel<2><<<dim3(64, 4, 2), 256, 0, stream>>>(num, nrm, Wout, obuf);
    } else {                                                 // NS = 1
        float* nrm = num + CHSZ;
        attn_kernel<32><<<dim3(33, 8, 1), 512, 0, stream>>>(q, k, v, num, nrm);
        out_kernel<1><<<dim3(64, 4, 2), 256, 0, stream>>>(num, nrm, Wout, obuf);
    }
    kmerge_kernel<<<dim3(1024), 256, 0, stream>>>(obuf, bout, out);
}